// Round 19
// baseline (741.300 us; speedup 1.0000x reference)
//
#include <hip/hip_runtime.h>
#include <stdint.h>

typedef unsigned short ushort_t;
typedef __attribute__((ext_vector_type(4))) float f32x4;
typedef __attribute__((ext_vector_type(8))) short bf16x8;

#define DEV __device__ __forceinline__

DEV ushort_t f2bf(float f) {                 // round-to-nearest-even f32->bf16
  uint32_t x = __float_as_uint(f);
  uint32_t r = (x + 0x7fffu + ((x >> 16) & 1u)) >> 16;
  return (ushort_t)r;
}

DEV f32x4 mfma16(bf16x8 a, bf16x8 b, f32x4 c) {
  return __builtin_amdgcn_mfma_f32_16x16x32_bf16(a, b, c, 0, 0, 0);
}

DEV bf16x8 ld_frag_lds(const ushort_t* p) {
  bf16x8 r;
  ((uint64_t*)&r)[0] = ((const uint64_t*)p)[0];
  ((uint64_t*)&r)[1] = ((const uint64_t*)p)[1];
  return r;
}
DEV bf16x8 ld_frag_g(const ushort_t* p) { return *(const bf16x8*)p; }

DEV void gload_lds16(const ushort_t* g, ushort_t* l) {   // 16B global->LDS DMA
  __builtin_amdgcn_global_load_lds((const __attribute__((address_space(1))) void*)g,
                                   (__attribute__((address_space(3))) void*)l, 16, 0, 0);
}

// ================= numpy-mimic f32 helpers =================
DEV float np_pw64(const float* a) {
  float r0 = a[0], r1 = a[1], r2 = a[2], r3 = a[3];
  float r4 = a[4], r5 = a[5], r6 = a[6], r7 = a[7];
  for (int i = 8; i < 64; i += 8) {
    r0 = __fadd_rn(r0, a[i]);     r1 = __fadd_rn(r1, a[i + 1]);
    r2 = __fadd_rn(r2, a[i + 2]); r3 = __fadd_rn(r3, a[i + 3]);
    r4 = __fadd_rn(r4, a[i + 4]); r5 = __fadd_rn(r5, a[i + 5]);
    r6 = __fadd_rn(r6, a[i + 6]); r7 = __fadd_rn(r7, a[i + 7]);
  }
  return __fadd_rn(__fadd_rn(__fadd_rn(r0, r1), __fadd_rn(r2, r3)),
                   __fadd_rn(__fadd_rn(r4, r5), __fadd_rn(r6, r7)));
}

// numpy einsum NPYV baseline SSE3 recipe (reverse-chained mul/add, hadd tree)
DEV float np_einsum_dot64(const float* __restrict__ a, const float* __restrict__ b) {
  float v0 = 0.f, v1 = 0.f, v2 = 0.f, v3 = 0.f;
#pragma unroll
  for (int B = 0; B < 4; B++) {
    const float* pa = a + B * 16;
    const float* pb = b + B * 16;
    float t;
    t  = __fadd_rn(__fmul_rn(pa[12], pb[12]), v0);
    t  = __fadd_rn(__fmul_rn(pa[8],  pb[8]),  t);
    t  = __fadd_rn(__fmul_rn(pa[4],  pb[4]),  t);
    v0 = __fadd_rn(__fmul_rn(pa[0],  pb[0]),  t);
    t  = __fadd_rn(__fmul_rn(pa[13], pb[13]), v1);
    t  = __fadd_rn(__fmul_rn(pa[9],  pb[9]),  t);
    t  = __fadd_rn(__fmul_rn(pa[5],  pb[5]),  t);
    v1 = __fadd_rn(__fmul_rn(pa[1],  pb[1]),  t);
    t  = __fadd_rn(__fmul_rn(pa[14], pb[14]), v2);
    t  = __fadd_rn(__fmul_rn(pa[10], pb[10]), t);
    t  = __fadd_rn(__fmul_rn(pa[6],  pb[6]),  t);
    v2 = __fadd_rn(__fmul_rn(pa[2],  pb[2]),  t);
    t  = __fadd_rn(__fmul_rn(pa[15], pb[15]), v3);
    t  = __fadd_rn(__fmul_rn(pa[11], pb[11]), t);
    t  = __fadd_rn(__fmul_rn(pa[7],  pb[7]),  t);
    v3 = __fadd_rn(__fmul_rn(pa[3],  pb[3]),  t);
  }
  return __fadd_rn(__fadd_rn(v0, v1), __fadd_rn(v2, v3));
}

DEV bool flt_lt(float a, float b) { return a < b || (b != b && a == a); }

// ---------- fused weight conversion (4 tensors) + tie-flag zero ----------
__global__ void wconv_k(const float* __restrict__ qkv_w, const float* __restrict__ proj_w,
                        const float* __restrict__ fc1_w, const float* __restrict__ fc2_w,
                        ushort_t* __restrict__ oq, ushort_t* __restrict__ op,
                        ushort_t* __restrict__ o1, ushort_t* __restrict__ o2,
                        int* __restrict__ tflag) {
  int i = blockIdx.x * 256 + threadIdx.x;
  if (i == 0) tflag[0] = 0;
  const int N0 = 2304 * 768, N1 = 768 * 768, N2 = 3072 * 768, N3 = 768 * 3072;
  if (i < N0) { oq[i] = f2bf(qkv_w[i]); return; }
  i -= N0;
  if (i < N1) { op[i] = f2bf(proj_w[i]); return; }
  i -= N1;
  if (i < N2) { o1[i] = f2bf(fc1_w[i]); return; }
  i -= N2;
  if (i < N3) o2[i] = f2bf(fc2_w[i]);
}

// ---------- LN1 np-mimic f32 (decision path), wave-parallel exact pairwise ----
__global__ __launch_bounds__(64) void lnm32_k(
    const float* __restrict__ x, const float* __restrict__ g, const float* __restrict__ bb,
    float* __restrict__ h32) {
  const int row = blockIdx.x, lane = threadIdx.x;
  __shared__ float xs[768];
  const float* xr = x + (size_t)row * 768;
  for (int c = lane; c < 768; c += 64) xs[c] = xr[c];
  __syncthreads();
  const int base = 96 * (lane >> 3) + (lane & 7);
  float v = xs[base];
#pragma unroll
  for (int t = 1; t < 12; t++) v = __fadd_rn(v, xs[base + 8 * t]);
#pragma unroll
  for (int w = 1; w <= 32; w <<= 1) v = __fadd_rn(v, __shfl_xor(v, w));
  const float mu = __fdiv_rn(__shfl(v, 0), 768.0f);            // np.mean
  float d0 = __fsub_rn(xs[base], mu);
  float sv = __fmul_rn(d0, d0);
#pragma unroll
  for (int t = 1; t < 12; t++) {
    float dd = __fsub_rn(xs[base + 8 * t], mu);
    sv = __fadd_rn(sv, __fmul_rn(dd, dd));
  }
#pragma unroll
  for (int w = 1; w <= 32; w <<= 1) sv = __fadd_rn(sv, __shfl_xor(sv, w));
  const float var = __fdiv_rn(__shfl(sv, 0), 768.0f);          // np.var
  const float sf = __fsqrt_rn(__fadd_rn(var, 1e-5f));          // sqrt(var+eps)
  float* hr = h32 + (size_t)row * 768;
  for (int c = lane; c < 768; c += 64) {
    float t = __fsub_rn(xs[c], mu);
    t = __fdiv_rn(t, sf);
    t = __fmul_rn(t, g[c]);
    t = __fadd_rn(t, bb[c]);
    hr[c] = t;
  }
}

// ---------- k = h @ Wk^T, kc=320-panel bit-exact, 64x64 tile, 8x4 regs ----------
__global__ __launch_bounds__(128) void kmetric32_k(
    const float* __restrict__ h32, const float* __restrict__ qkv_w, float* __restrict__ k32) {
  __shared__ float hs[64][68];
  __shared__ float wsd[64][68];
  const int tid = threadIdx.x;
  const int tx = tid & 15, ty = tid >> 4;        // tx: 16 ch-slots, ty: 8 tok-slots
  const int tok0 = blockIdx.x * 64, ch0 = blockIdx.y * 64;
  float acc[8][4];
  float part[8][4];
#pragma unroll
  for (int i = 0; i < 8; i++)
#pragma unroll
    for (int j = 0; j < 4; j++) { acc[i][j] = 0.f; part[i][j] = 0.f; }

  for (int chunk = 0; chunk < 12; chunk++) {
    const int c0 = chunk * 64;
    __syncthreads();
#pragma unroll
    for (int e = 0; e < 8; e++) {          // stage h: 64x64 floats as float4
      int flat = e * 128 + tid;
      int r = flat >> 4, c4 = (flat & 15) << 2;
      *(float4*)&hs[r][c4] = *(const float4*)&h32[(size_t)(tok0 + r) * 768 + c0 + c4];
    }
#pragma unroll
    for (int e = 0; e < 8; e++) {          // stage w: 64x64 floats as float4
      int flat = e * 128 + tid;
      int r = flat >> 4, c4 = (flat & 15) << 2;
      *(float4*)&wsd[r][c4] = *(const float4*)&qkv_w[(size_t)(768 + ch0 + r) * 768 + c0 + c4];
    }
    __syncthreads();
#pragma unroll 1
    for (int cq = 0; cq < 16; cq++) {      // 4-wide c quads, ascending
      float4 hv[8], wv[4];
#pragma unroll
      for (int i = 0; i < 8; i++) hv[i] = *(const float4*)&hs[ty + 8 * i][cq << 2];
#pragma unroll
      for (int j = 0; j < 4; j++) wv[j] = *(const float4*)&wsd[tx + 16 * j][cq << 2];
#pragma unroll
      for (int u = 0; u < 4; u++)          // ascending c within quad
#pragma unroll
        for (int i = 0; i < 8; i++) {
          float hvu = ((const float*)&hv[i])[u];
#pragma unroll
          for (int j = 0; j < 4; j++)
            acc[i][j] = __fmaf_rn(hvu, ((const float*)&wv[j])[u], acc[i][j]);
        }
    }
    if (chunk == 4) {                      // panel A done (c=320)
#pragma unroll
      for (int i = 0; i < 8; i++)
#pragma unroll
        for (int j = 0; j < 4; j++) { part[i][j] = acc[i][j]; acc[i][j] = 0.f; }
    } else if (chunk == 9) {               // panel B done (c=640): part = A + B
#pragma unroll
      for (int i = 0; i < 8; i++)
#pragma unroll
        for (int j = 0; j < 4; j++) { part[i][j] = __fadd_rn(part[i][j], acc[i][j]); acc[i][j] = 0.f; }
    }
  }
#pragma unroll
  for (int i = 0; i < 8; i++)              // final = (A+B) + C
#pragma unroll
    for (int j = 0; j < 4; j++) {
      size_t idx = (size_t)(tok0 + ty + 8 * i) * 768 + ch0 + tx + 16 * j;
      k32[idx] = __fadd_rn(part[i][j], acc[i][j]);
    }
}

// ---------- metric = k.mean(heads) sequential, L2-norm pw64 ----------
__global__ __launch_bounds__(64) void hmean32_k(
    const float* __restrict__ k32, float* __restrict__ m32) {
  const int row = blockIdx.x, lane = threadIdx.x;
  __shared__ float sm[64];
  const float* kr = k32 + (size_t)row * 768;
  float m = kr[lane];
  for (int hh = 1; hh < 12; hh++) m = __fadd_rn(m, kr[hh * 64 + lane]);
  m = __fdiv_rn(m, 12.0f);
  sm[lane] = __fmul_rn(m, m);
  __syncthreads();
  float nrm = __fsqrt_rn(np_pw64(sm));
  m32[(size_t)row * 64 + lane] = __fdiv_rn(m, nrm);
}

// ---------- scores: FMA screening + exact np.einsum only for candidates ------
// Sound bound: |fma_chain - recipe_chain| < 1e-5 for unit vectors; THR=1e-4.
// All dots that can be the max get the exact recipe; first-max semantics kept.
__global__ __launch_bounds__(256) void scores32_k(
    const float* __restrict__ m32, float* __restrict__ nmax, int* __restrict__ nidx) {
  const int b = blockIdx.y, i0 = blockIdx.x * 4;
  const int tid = threadIdx.x, ig = tid >> 6, lane = tid & 63;
  const int i = i0 + ig;
  const float* mb = m32 + (size_t)b * 1568 * 64;
  __shared__ float av[4][64];
  __shared__ float appx[4][784];
  __shared__ float bv[4][64];
  __shared__ int bj[4][64];
  av[ig][lane] = mb[(size_t)(2 * i) * 64 + lane];
  __syncthreads();
  const float* a = av[ig];
  float amax = -1e30f;
  for (int j = lane; j < 784; j += 64) {     // phase 1: fused-FMA screening
    const float* br = mb + (size_t)(2 * j + 1) * 64;
    float d = 0.f;
#pragma unroll
    for (int c = 0; c < 64; c++) d = __fmaf_rn(a[c], br[c], d);
    appx[ig][j] = d;
    amax = fmaxf(amax, d);
  }
#pragma unroll
  for (int w = 1; w < 64; w <<= 1) amax = fmaxf(amax, __shfl_xor(amax, w));
  const float thr = amax - 1e-4f;
  float best = -1e30f; int bidx = 0;
  for (int j = lane; j < 784; j += 64) {     // phase 2: exact recipe, candidates only
    if (appx[ig][j] >= thr) {
      const float* br = mb + (size_t)(2 * j + 1) * 64;
      float dot = np_einsum_dot64(a, br);
      if (dot > best) { best = dot; bidx = j; }   // ascending j -> first max kept
    }
  }
  bv[ig][lane] = best; bj[ig][lane] = bidx;
  __syncthreads();
  if (lane == 0) {
    float bb_ = bv[ig][0]; int bi_ = bj[ig][0];
    for (int l = 1; l < 64; l++)
      if (bv[ig][l] > bb_ || (bv[ig][l] == bb_ && bj[ig][l] < bi_)) { bb_ = bv[ig][l]; bi_ = bj[ig][l]; }
    nmax[b * 784 + i] = bb_;                 // max exact; argmax = first max
    nidx[b * 784 + i] = bi_;
  }
}

// ---------- FAST PATH: parallel stable-descending rank sort + tie detection ----
__global__ __launch_bounds__(256) void rank_fast_k(
    const float* __restrict__ nmax, const int* __restrict__ nidx,
    int* __restrict__ eidx, int* __restrict__ didx, int* __restrict__ tflag) {
  const int b = blockIdx.x;
  __shared__ float sv[784];
  __shared__ int s_ei[784];
  for (int i = threadIdx.x; i < 784; i += 256) sv[i] = nmax[b * 784 + i];
  __syncthreads();
  for (int i = threadIdx.x; i < 784; i += 256) {
    float v = sv[i]; int rank = 0;
    for (int j = 0; j < 784; j++) {
      float u = sv[j];
      rank += (u > v || (u == v && j < i)) ? 1 : 0;
    }
    s_ei[rank] = i;
  }
  __syncthreads();
  for (int r = threadIdx.x; r < 783; r += 256)
    if (sv[s_ei[r]] == sv[s_ei[r + 1]]) atomicOr(tflag, 1);
  for (int i = threadIdx.x; i < 784; i += 256) eidx[b * 784 + i] = s_ei[i];
  for (int i = threadIdx.x; i < 256; i += 256) didx[b * 256 + i] = nidx[b * 784 + s_ei[i]];
}

// ---------- SLOW PATH: faithful numpy aquicksort; runs only if ties exist ----
__global__ __launch_bounds__(64) void argsort_serial_k(
    const float* __restrict__ nmax, const int* __restrict__ nidx,
    int* __restrict__ eidx, int* __restrict__ didx, const int* __restrict__ tflag) {
  if (tflag[0] == 0) return;                 // no exact ties: fast path already exact
  const int b = blockIdx.x;
  __shared__ float sv[784];
  __shared__ int tos[784];
  for (int i = threadIdx.x; i < 784; i += 64) { sv[i] = -nmax[b * 784 + i]; tos[i] = i; }
  __syncthreads();
  if (threadIdx.x == 0) {
    const int num = 784;
    int stck[100]; int sptr = 0;
    int dpth[100]; int psd = 0;
    int cdepth; { int n = num, m = 0; while (n >>= 1) m++; cdepth = m * 2; }  // 18
    int pl = 0, pr = num - 1;
    for (;;) {
      if (cdepth < 0) {                       // aheapsort fallback (numpy-faithful)
        int n = pr - pl + 1;
        int* a = &tos[pl] - 1;                // 1-based
        for (int l = n >> 1; l > 0; --l) {
          int tmp = a[l];
          int i2 = l, j2 = l * 2;
          while (j2 <= n) {
            if (j2 < n && flt_lt(sv[a[j2]], sv[a[j2 + 1]])) j2++;
            if (flt_lt(sv[tmp], sv[a[j2]])) { a[i2] = a[j2]; i2 = j2; j2 += j2; }
            else break;
          }
          a[i2] = tmp;
        }
        for (int n2 = n; n2 > 1;) {
          int tmp = a[n2]; a[n2] = a[1]; n2--;
          int i2 = 1, j2 = 2;
          while (j2 <= n2) {
            if (j2 < n2 && flt_lt(sv[a[j2]], sv[a[j2 + 1]])) j2++;
            if (flt_lt(sv[tmp], sv[a[j2]])) { a[i2] = a[j2]; i2 = j2; j2 += j2; }
            else break;
          }
          a[i2] = tmp;
        }
        goto stack_pop;
      }
      while ((pr - pl) > 15) {                // SMALL_QUICKSORT = 15
        int t_;
        int pm = pl + ((pr - pl) >> 1);
        if (flt_lt(sv[tos[pm]], sv[tos[pl]])) { t_ = tos[pm]; tos[pm] = tos[pl]; tos[pl] = t_; }
        if (flt_lt(sv[tos[pr]], sv[tos[pm]])) { t_ = tos[pr]; tos[pr] = tos[pm]; tos[pm] = t_; }
        if (flt_lt(sv[tos[pm]], sv[tos[pl]])) { t_ = tos[pm]; tos[pm] = tos[pl]; tos[pl] = t_; }
        float vp = sv[tos[pm]];
        int pi = pl, pj = pr - 1;
        t_ = tos[pm]; tos[pm] = tos[pj]; tos[pj] = t_;
        for (;;) {
          do { ++pi; } while (flt_lt(sv[tos[pi]], vp));
          do { --pj; } while (flt_lt(vp, sv[tos[pj]]));
          if (pi >= pj) break;
          t_ = tos[pi]; tos[pi] = tos[pj]; tos[pj] = t_;
        }
        int pk = pr - 1;
        t_ = tos[pi]; tos[pi] = tos[pk]; tos[pk] = t_;
        if (pi - pl < pr - pi) { stck[sptr++] = pi + 1; stck[sptr++] = pr; pr = pi - 1; }
        else                   { stck[sptr++] = pl; stck[sptr++] = pi - 1; pl = pi + 1; }
        dpth[psd++] = --cdepth;
      }
      for (int pi2 = pl + 1; pi2 <= pr; pi2++) {   // insertion sort tail
        int vi = tos[pi2]; float vp2 = sv[vi];
        int pj2 = pi2, pk2 = pi2 - 1;
        while (pj2 > pl && flt_lt(vp2, sv[tos[pk2]])) { tos[pj2--] = tos[pk2--]; }
        tos[pj2] = vi;
      }
stack_pop:
      if (sptr == 0) break;
      pr = stck[--sptr]; pl = stck[--sptr];
      cdepth = dpth[--psd];
    }
  }
  __syncthreads();
  for (int i = threadIdx.x; i < 784; i += 64) eidx[b * 784 + i] = tos[i];
  for (int i = threadIdx.x; i < 256; i += 64) didx[b * 256 + i] = nidx[b * 784 + tos[i]];
}

// ---------- LayerNorm -> bf16 (content path) ----------
__global__ __launch_bounds__(256) void ln_k(
    const float* __restrict__ x, const float* __restrict__ g, const float* __restrict__ bb,
    ushort_t* __restrict__ hout, const float* __restrict__ size, float* __restrict__ ls) {
  const int row = blockIdx.x;
  const float* xr = x + (size_t)row * 768;
  const int t = threadIdx.x;
  float v0 = xr[t], v1 = xr[t + 256], v2 = xr[t + 512];
  float s = v0 + v1 + v2;
  float ss = v0 * v0 + v1 * v1 + v2 * v2;
#pragma unroll
  for (int w = 32; w >= 1; w >>= 1) { s += __shfl_down(s, w); ss += __shfl_down(ss, w); }
  __shared__ float red[8];
  const int wv = t >> 6;
  if ((t & 63) == 0) { red[wv] = s; red[4 + wv] = ss; }
  __syncthreads();
  s  = red[0] + red[1] + red[2] + red[3];
  ss = red[4] + red[5] + red[6] + red[7];
  const float mu = s * (1.f / 768.f);
  const float rstd = rsqrtf(ss * (1.f / 768.f) - mu * mu + 1e-5f);
  ushort_t* hr = hout + (size_t)row * 768;
  hr[t]       = f2bf((v0 - mu) * rstd * g[t]       + bb[t]);
  hr[t + 256] = f2bf((v1 - mu) * rstd * g[t + 256] + bb[t + 256]);
  hr[t + 512] = f2bf((v2 - mu) * rstd * g[t + 512] + bb[t + 512]);
  if (ls != nullptr && t == 0) ls[row] = logf(size[row]);
}

// ---------- GEMM: C[M,N] = A[M,K](bf16) @ W[N,K]^T(bf16), epilogue per EPI ----------
template <int EPI>
__global__ __launch_bounds__(256) void gemm_bt(
    const ushort_t* __restrict__ A, const ushort_t* __restrict__ W, int K,
    const float* __restrict__ bias0, const float* __restrict__ bias1,
    const float* __restrict__ res,
    ushort_t* __restrict__ ob0, ushort_t* __restrict__ ob1, ushort_t* __restrict__ ob2,
    float* __restrict__ of) {
  __shared__ ushort_t As[128 * 32];   // unpadded: required by global_load_lds
  __shared__ ushort_t Bs[128 * 32];
  const int tid = threadIdx.x;
  const int lane = tid & 63, wave = tid >> 6;
  const int wm = (wave >> 1) * 64, wn = (wave & 1) * 64;
  const int fr = lane & 15, kb = (lane >> 4) * 8;
  const int bm = blockIdx.x * 128, bn = blockIdx.y * 128;
  const int rr = tid >> 2;                  // 0..63 (row within chunk)
  const int cb = (tid & 3) * 8;             // ushort col offset (16B quanta)
  ushort_t* ldA0 = As + wave * 512;         // chunk 0 wave base (512 ush = 1KB)
  ushort_t* ldA1 = As + 2048 + wave * 512;  // chunk 1
  ushort_t* ldB0 = Bs + wave * 512;
  ushort_t* ldB1 = Bs + 2048 + wave * 512;
  f32x4 acc[4][4] = {};
  for (int k0 = 0; k0 < K; k0 += 32) {
    __syncthreads();                        // previous tile reads done
    gload_lds16(A + (size_t)(bm + rr) * K + k0 + cb,      ldA0);
    gload_lds16(A + (size_t)(bm + 64 + rr) * K + k0 + cb, ldA1);
    gload_lds16(W + (size_t)(bn + rr) * K + k0 + cb,      ldB0);
    gload_lds16(W + (size_t)(bn + 64 + rr) * K + k0 + cb, ldB1);
    __syncthreads();                        // vmcnt(0) drain: data in LDS
    bf16x8 af[4], bfr[4];
#pragma unroll
    for (int i = 0; i < 4; i++) af[i]  = ld_frag_lds(&As[(wm + i * 16 + fr) * 32 + kb]);
#pragma unroll
    for (int i = 0; i < 4; i++) bfr[i] = ld_frag_lds(&Bs[(wn + i * 16 + fr) * 32 + kb]);
#pragma unroll
    for (int mi = 0; mi < 4; mi++)
#pragma unroll
      for (int ni = 0; ni < 4; ni++)
        acc[mi][ni] = mfma16(af[mi], bfr[ni], acc[mi][ni]);
  }
#pragma unroll
  for (int mi = 0; mi < 4; mi++)
#pragma unroll
    for (int ni = 0; ni < 4; ni++)
#pragma unroll
      for (int e = 0; e < 4; e++) {
        int m = bm + wm + mi * 16 + (lane >> 4) * 4 + e;
        int j = bn + wn + ni * 16 + fr;
        float val = acc[mi][ni][e];
        if constexpr (EPI == 0) {  // qkv -> q,k (B,H,N,D) ; v -> vt (B,H,D,N)
          int which = j / 768;
          int loc = j - which * 768;
          int hh = loc >> 6, d = loc & 63;
          unsigned um = (unsigned)m;
          unsigned b = um / 1568u;
          unsigned n = um - b * 1568u;
          if (which == 0) {
            val = (val + bias0[loc]) * 0.125f;
            ob0[(((size_t)b * 12 + hh) * 1568 + n) * 64 + d] = f2bf(val);
          } else if (which == 1) {
            ob1[(((size_t)b * 12 + hh) * 1568 + n) * 64 + d] = f2bf(val);
          } else {
            val += bias1[loc];
            ob2[(((size_t)b * 12 + hh) * 64 + d) * 1568 + n] = f2bf(val);
          }
        } else if constexpr (EPI == 1) {        // proj: + bias + x residual -> f32
          size_t idx = (size_t)m * 768 + j;
          of[idx] = val + bias0[j] + res[idx];
        } else if constexpr (EPI == 2) {        // fc1: + bias, exact GELU -> bf16
          float v = val + bias0[j];
          v = 0.5f * v * (1.0f + erff(v * 0.70710678118654752f));
          ob0[(size_t)m * 3072 + j] = f2bf(v);
        } else {                                // fc2: + bias + xm (in-place d_out)
          size_t idx = (size_t)m * 768 + j;
          of[idx] = val + bias0[j] + of[idx];
        }
      }
}

// ---------- flash attention: 7 waves/block share K/V via LDS (7x reuse) ----------
__global__ __launch_bounds__(448) void attn_k(
    const ushort_t* __restrict__ q, const ushort_t* __restrict__ k,
    const ushort_t* __restrict__ vt, const float* __restrict__ ls,
    ushort_t* __restrict__ o) {
  const int h = blockIdx.y, b = blockIdx.z;
  const int tid = threadIdx.x, wave = tid >> 6, lane = tid & 63;
  const int fr = lane & 15, hi = lane >> 4, kb = hi * 8;
  const ushort_t* qb  = q  + (size_t)(b * 12 + h) * 1568 * 64;
  const ushort_t* kbp = k  + (size_t)(b * 12 + h) * 1568 * 64;
  const ushort_t* vtb = vt + (size_t)(b * 12 + h) * 64 * 1568;
  const float* lsb = ls + b * 1568;
  const int q0 = (blockIdx.x * 7 + wave) * 16;   // 14*7 = 98 q-tiles exact
  __shared__ ushort_t Ks[2][32][68];   // [buf][key][d]   (+4 pad)
  __shared__ ushort_t Vs[2][64][36];   // [buf][d][key]   (+4 pad)
  __shared__ ushort_t Pls[7][16][36];  // per-wave P
  bf16x8 aq0 = ld_frag_g(qb + (size_t)(q0 + fr) * 64 + kb);
  bf16x8 aq1 = ld_frag_g(qb + (size_t)(q0 + fr) * 64 + 32 + kb);
  float m_r = -1e30f, l_r = 0.f;
  f32x4 oacc[4] = {};
  const bool doK = (tid < 256);
  const int krow = tid >> 3, kcol = (tid & 7) * 8;
  const int vtid = tid - 192;
  const bool doV = (vtid >= 0);
  const int vrow = vtid >> 2, vcol = (vtid & 3) * 8;
  if (doK) {
    uint4 kv = *(const uint4*)(kbp + (size_t)krow * 64 + kcol);
    *(uint2*)&Ks[0][krow][kcol]     = make_uint2(kv.x, kv.y);
    *(uint2*)&Ks[0][krow][kcol + 4] = make_uint2(kv.z, kv.w);
  }
  if (doV) {
    uint4 vv = *(const uint4*)(vtb + (size_t)vrow * 1568 + vcol);
    *(uint2*)&Vs[0][vrow][vcol]     = make_uint2(vv.x, vv.y);
    *(uint2*)&Vs[0][vrow][vcol + 4] = make_uint2(vv.z, vv.w);
  }
  __syncthreads();
  for (int kt = 0; kt < 49; kt++) {
    const int key0 = kt * 32;
    const int cur = kt & 1;
    uint4 kvn, vvn;                        // issue next-tile loads early (T14)
    if (kt < 48) {
      if (doK) kvn = *(const uint4*)(kbp + (size_t)(key0 + 32 + krow) * 64 + kcol);
      if (doV) vvn = *(const uint4*)(vtb + (size_t)vrow * 1568 + key0 + 32 + vcol);
    }
    bf16x8 c0a = ld_frag_lds(&Ks[cur][fr][kb]);
    bf16x8 c0b = ld_frag_lds(&Ks[cur][fr][32 + kb]);
    bf16x8 c1a = ld_frag_lds(&Ks[cur][16 + fr][kb]);
    bf16x8 c1b = ld_frag_lds(&Ks[cur][16 + fr][32 + kb]);
    f32x4 sl = {0, 0, 0, 0}, sh = {0, 0, 0, 0};
    sl = mfma16(c0a, aq0, sl); sl = mfma16(c0b, aq1, sl);
    sh = mfma16(c1a, aq0, sh); sh = mfma16(c1b, aq1, sh);
    float4 lsl = *(const float4*)&lsb[key0 + hi * 4];
    float4 lsh = *(const float4*)&lsb[key0 + 16 + hi * 4];
    float v0 = sl[0] + lsl.x, v1 = sl[1] + lsl.y, v2 = sl[2] + lsl.z, v3 = sl[3] + lsl.w;
    float v4 = sh[0] + lsh.x, v5 = sh[1] + lsh.y, v6 = sh[2] + lsh.z, v7 = sh[3] + lsh.w;
    float mx = fmaxf(fmaxf(fmaxf(v0, v1), fmaxf(v2, v3)),
                     fmaxf(fmaxf(v4, v5), fmaxf(v6, v7)));
    mx = fmaxf(mx, __shfl_xor(mx, 16));
    mx = fmaxf(mx, __shfl_xor(mx, 32));    // row max over 32 keys
    if (!__all(mx <= m_r)) {               // exact defer-max
      float mnew = fmaxf(m_r, mx);
      float corr = __expf(m_r - mnew);
      m_r = mnew;
      l_r *= corr;
      float cb0 = __shfl(corr, hi * 4 + 0);
      float cb1 = __shfl(corr, hi * 4 + 1);
      float cb2 = __shfl(corr, hi * 4 + 2);
      float cb3 = __shfl(corr, hi * 4 + 3);
#pragma unroll
      for (int dt = 0; dt < 4; dt++) {
        oacc[dt][0] *= cb0; oacc[dt][1] *= cb1;
        oacc[dt][2] *= cb2; oacc[dt][3] *= cb3;
      }
    }
    float p0 = __expf(v0 - m_r), p1 = __expf(v1 - m_r);
    float p2 = __expf(v2 - m_r), p3 = __expf(v3 - m_r);
    float p4 = __expf(v4 - m_r), p5 = __expf(v5 - m_r);
    float p6 = __expf(v6 - m_r), p7 = __expf(v7 - m_r);
    float ps = ((p0 + p1) + (p2 + p3)) + ((p4 + p5) + (p6 + p7));
    ps += __shfl_xor(ps, 16);
    ps += __shfl_xor(ps, 32);
    l_r += ps;
    uint32_t w0 = (uint32_t)f2bf(p0) | ((uint32_t)f2bf(p1) << 16);
    uint32_t w1 = (uint32_t)f2bf(p2) | ((uint32_t)f2bf(p3) << 16);
    uint32_t w2 = (uint32_t)f2bf(p4) | ((uint32_t)f2bf(p5) << 16);
    uint32_t w3 = (uint32_t)f2bf(p6) | ((uint32_t)f2bf(p7) << 16);
    *(uint2*)&Pls[wave][fr][hi * 4]      = make_uint2(w0, w1);
    *(uint2*)&Pls[wave][fr][16 + hi * 4] = make_uint2(w2, w3);
    bf16x8 pa = ld_frag_lds(&Pls[wave][fr][kb]);
#pragma unroll
    for (int dt = 0; dt < 4; dt++) {
      bf16x8 bvv = ld_frag_lds(&Vs[cur][dt * 16 + fr][kb]);
      oacc[dt] = mfma16(pa, bvv, oacc[dt]);
    }
    if (kt < 48) {
      if (doK) {
        *(uint2*)&Ks[cur ^ 1][krow][kcol]     = make_uint2(kvn.x, kvn.y);
        *(uint2*)&Ks[cur ^ 1][krow][kcol + 4] = make_uint2(kvn.z, kvn.w);
      }
      if (doV) {
        *(uint2*)&Vs[cur ^ 1][vrow][vcol]     = make_uint2(vvn.x, vvn.y);
        *(uint2*)&Vs[cur ^ 1][vrow][vcol + 4] = make_uint2(vvn.z, vvn.w);
      }
    }
    __syncthreads();
  }
  float lb[4];
#pragma unroll
  for (int e = 0; e < 4; e++) lb[e] = __shfl(l_r, hi * 4 + e);
  const size_t obase = ((size_t)b * 1568 + q0) * 768 + h * 64;
#pragma unroll
  for (int dt = 0; dt < 4; dt++)
#pragma unroll
    for (int e = 0; e < 4; e++)
      o[obase + (size_t)(hi * 4 + e) * 768 + dt * 16 + fr] = f2bf(oacc[dt][e] / lb[e]);
}

// ---------- token merge: deterministic gather (hoisted src-list scan) ----------
__global__ __launch_bounds__(256) void merge_k(
    const float* __restrict__ xa, const float* __restrict__ size,
    const int* __restrict__ eidx, const int* __restrict__ didx,
    float* __restrict__ xm) {
  const int b = blockIdx.y, t = blockIdx.x;
  const float* xab = xa + (size_t)b * 1568 * 768;
  const float* szb = size + (size_t)b * 1568;
  const int* ei = eidx + b * 784;
  const int* di = didx + b * 256;
  float* outr = xm + ((size_t)b * 1312 + t) * 768;
  if (t < 528) {
    int tok = 2 * ei[256 + t];
    float s = szb[tok];
    const float* xr = xab + (size_t)tok * 768;
    for (int c = threadIdx.x; c < 768; c += 256) outr[c] = (xr[c] * s) / s;
  } else {
    int j = t - 528;
    int tok = 2 * j + 1;
    __shared__ int lst[256];
    __shared__ int s_cnt;
    __shared__ float s_sn;
    if (threadIdx.x == 0) {
      int cnt = 0;
      float sn = szb[tok];
      for (int s_ = 0; s_ < 256; s_++)
        if (di[s_] == j) { int st = 2 * ei[s_]; lst[cnt++] = st; sn += szb[st]; }
      s_cnt = cnt; s_sn = sn;
    }
    __syncthreads();
    const int n = s_cnt;
    const float sn = s_sn;
    for (int c = threadIdx.x; c < 768; c += 256) {
      float val = xab[(size_t)tok * 768 + c] * szb[tok];
      for (int l = 0; l < n; l++) {      // ascending s_ order preserved
        int st = lst[l];
        val += xab[(size_t)st * 768 + c] * szb[st];
      }
      outr[c] = val / sn;
    }
  }
}

// ---------- workspace layout ----------
static const size_t OFF_QKVW  = 0;                          // 2304*768*2
static const size_t OFF_PROJW = OFF_QKVW  + 3538944;        // 768*768*2
static const size_t OFF_FC1W  = OFF_PROJW + 1179648;        // 3072*768*2
static const size_t OFF_FC2W  = OFF_FC1W  + 4718592;        // 768*3072*2
static const size_t OFF_LS    = OFF_FC2W  + 4718592;        // 6272*4
static const size_t OFF_MET   = OFF_LS    + 25088;          // 6272*64*4 (m32)
static const size_t OFF_NMAX  = OFF_MET   + 1605632;        // 4*784*4
static const size_t OFF_NIDX  = OFF_NMAX  + 12544;
static const size_t OFF_EIDX  = OFF_NIDX  + 12544;
static const size_t OFF_DIDX  = OFF_EIDX  + 12544;          // 4*256*4
static const size_t OFF_TFLAG = OFF_DIDX  + 4096;           // tie flag (+pad)
static const size_t OFF_H     = OFF_TFLAG + 256;            // h_bf16 (6272*768*2)
static const size_t OFF_BIG   = OFF_H     + 9633792;        // q,k,vt | h3 | k32 alias
static const size_t OFF_O     = OFF_BIG   + 32243712;       // o_bf16
static const size_t OFF_XA    = OFF_O     + 9633792;        // xa f32 | h32 alias
static const size_t WS_NEED   = OFF_XA    + 19267584;       // ~86.6 MB

extern "C" void kernel_launch(void* const* d_in, const int* in_sizes, int n_in,
                              void* d_out, int out_size, void* d_ws, size_t ws_size,
                              hipStream_t stream) {
  (void)in_sizes; (void)n_in; (void)out_size;
  if (ws_size < WS_NEED) return;

  const float* x      = (const float*)d_in[0];
  const float* size_p = (const float*)d_in[1];
  const float* qkv_w  = (const float*)d_in[2];
  const float* q_bias = (const float*)d_in[3];
  const float* v_bias = (const float*)d_in[4];
  const float* proj_w = (const float*)d_in[5];
  const float* proj_b = (const float*)d_in[6];
  const float* ln1_g  = (const float*)d_in[7];
  const float* ln1_b  = (const float*)d_in[8];
  const float* ln2_g  = (const float*)d_in[9];
  const float* ln2_b  = (const float*)d_in[10];
  const float* fc1_w  = (const float*)d_in[11];
  const float* fc1_b  = (const float*)d_in[12];
  const float* fc2_w  = (const float*)d_in[13];
  const float* fc2_b  = (const float*)d_in[14];

  char* ws = (char*)d_ws;
  ushort_t* qkvw_bf = (ushort_t*)(ws + OFF_QKVW);
  ushort_t* projw_bf= (ushort_t*)(ws + OFF_PROJW);
  ushort_t* fc1w_bf = (ushort_t*)(ws + OFF_FC1W);
  ushort_t* fc2w_bf = (ushort_t*)(ws + OFF_FC2W);
  float*    ls      = (float*)   (ws + OFF_LS);
  float*    m32     = (float*)   (ws + OFF_MET);
  float*    nmax    = (float*)   (ws + OFF_NMAX);
  int*      nidx    = (int*)     (ws + OFF_NIDX);
  int*      eidx    = (int*)     (ws + OFF_EIDX);
  int*      didx    = (int*)     (ws + OFF_DIDX);
  int*      tflag   = (int*)     (ws + OFF_TFLAG);
  ushort_t* h_bf    = (ushort_t*)(ws + OFF_H);
  ushort_t* q_bf    = (ushort_t*)(ws + OFF_BIG);
  ushort_t* k_bf    = (ushort_t*)(ws + OFF_BIG + 9633792);
  ushort_t* vt_bf   = (ushort_t*)(ws + OFF_BIG + 2 * 9633792);
  ushort_t* h3_bf   = (ushort_t*)(ws + OFF_BIG);
  float*    k32     = (float*)   (ws + OFF_BIG);   // alias: dead before gemm<0>
  ushort_t* o_bf    = (ushort_t*)(ws + OFF_O);
  float*    xa      = (float*)   (ws + OFF_XA);
  float*    h32     = (float*)   (ws + OFF_XA);    // alias: dead before gemm<1>
  float*    out     = (float*)d_out;

  // weights -> bf16 (fused, also zeroes tie flag)
  wconv_k<<<27648, 256, 0, stream>>>(qkv_w, proj_w, fc1_w, fc2_w,
                                     qkvw_bf, projw_bf, fc1w_bf, fc2w_bf, tflag);

  // ---- decision path: exact numpy-f32 mimic (kc=320 GEMM panels) ----
  lnm32_k<<<6272, 64, 0, stream>>>(x, ln1_g, ln1_b, h32);
  kmetric32_k<<<dim3(98, 12), 128, 0, stream>>>(h32, qkv_w, k32);
  hmean32_k<<<6272, 64, 0, stream>>>(k32, m32);
  scores32_k<<<dim3(196, 4), 256, 0, stream>>>(m32, nmax, nidx);
  rank_fast_k<<<4, 256, 0, stream>>>(nmax, nidx, eidx, didx, tflag);        // fast path
  argsort_serial_k<<<4, 64, 0, stream>>>(nmax, nidx, eidx, didx, tflag);    // tie fallback

  // ---- content path: bf16 MFMA ----
  ln_k<<<6272, 256, 0, stream>>>(x, ln1_g, ln1_b, h_bf, size_p, ls);
  gemm_bt<0><<<dim3(49, 18), 256, 0, stream>>>(h_bf, qkvw_bf, 768, q_bias, v_bias,
                                               nullptr, q_bf, k_bf, vt_bf, nullptr);
  attn_k<<<dim3(14, 12, 4), 448, 0, stream>>>(q_bf, k_bf, vt_bf, ls, o_bf);
  gemm_bt<1><<<dim3(49, 6), 256, 0, stream>>>(o_bf, projw_bf, 768, proj_b, nullptr,
                                              x, nullptr, nullptr, nullptr, xa);

  merge_k<<<dim3(1312, 4), 256, 0, stream>>>(xa, size_p, eidx, didx, out);

  ln_k<<<5248, 256, 0, stream>>>(out, ln2_g, ln2_b, h_bf, nullptr, nullptr);
  gemm_bt<2><<<dim3(41, 24), 256, 0, stream>>>(h_bf, fc1w_bf, 768, fc1_b, nullptr,
                                               nullptr, h3_bf, nullptr, nullptr, nullptr);
  gemm_bt<3><<<dim3(41, 6), 256, 0, stream>>>(h3_bf, fc2w_bf, 3072, fc2_b, nullptr,
                                              nullptr, nullptr, nullptr, nullptr, out);
}

// Round 20
// 731.711 us; speedup vs baseline: 1.0131x; 1.0131x over previous
//
#include <hip/hip_runtime.h>
#include <stdint.h>

typedef unsigned short ushort_t;
typedef __attribute__((ext_vector_type(4))) float f32x4;
typedef __attribute__((ext_vector_type(8))) short bf16x8;

#define DEV __device__ __forceinline__

DEV ushort_t f2bf(float f) {                 // round-to-nearest-even f32->bf16
  uint32_t x = __float_as_uint(f);
  uint32_t r = (x + 0x7fffu + ((x >> 16) & 1u)) >> 16;
  return (ushort_t)r;
}

DEV f32x4 mfma16(bf16x8 a, bf16x8 b, f32x4 c) {
  return __builtin_amdgcn_mfma_f32_16x16x32_bf16(a, b, c, 0, 0, 0);
}

DEV bf16x8 ld_frag_lds(const ushort_t* p) {
  bf16x8 r;
  ((uint64_t*)&r)[0] = ((const uint64_t*)p)[0];
  ((uint64_t*)&r)[1] = ((const uint64_t*)p)[1];
  return r;
}
DEV bf16x8 ld_frag_g(const ushort_t* p) { return *(const bf16x8*)p; }

DEV void gload_lds16(const ushort_t* g, ushort_t* l) {   // 16B global->LDS DMA
  __builtin_amdgcn_global_load_lds((const __attribute__((address_space(1))) void*)g,
                                   (__attribute__((address_space(3))) void*)l, 16, 0, 0);
}

// numpy einsum NPYV baseline SSE3 recipe (reverse-chained mul/add, hadd tree)
DEV float np_einsum_dot64(const float* __restrict__ a, const float* __restrict__ b) {
  float v0 = 0.f, v1 = 0.f, v2 = 0.f, v3 = 0.f;
#pragma unroll
  for (int B = 0; B < 4; B++) {
    const float* pa = a + B * 16;
    const float* pb = b + B * 16;
    float t;
    t  = __fadd_rn(__fmul_rn(pa[12], pb[12]), v0);
    t  = __fadd_rn(__fmul_rn(pa[8],  pb[8]),  t);
    t  = __fadd_rn(__fmul_rn(pa[4],  pb[4]),  t);
    v0 = __fadd_rn(__fmul_rn(pa[0],  pb[0]),  t);
    t  = __fadd_rn(__fmul_rn(pa[13], pb[13]), v1);
    t  = __fadd_rn(__fmul_rn(pa[9],  pb[9]),  t);
    t  = __fadd_rn(__fmul_rn(pa[5],  pb[5]),  t);
    v1 = __fadd_rn(__fmul_rn(pa[1],  pb[1]),  t);
    t  = __fadd_rn(__fmul_rn(pa[14], pb[14]), v2);
    t  = __fadd_rn(__fmul_rn(pa[10], pb[10]), t);
    t  = __fadd_rn(__fmul_rn(pa[6],  pb[6]),  t);
    v2 = __fadd_rn(__fmul_rn(pa[2],  pb[2]),  t);
    t  = __fadd_rn(__fmul_rn(pa[15], pb[15]), v3);
    t  = __fadd_rn(__fmul_rn(pa[11], pb[11]), t);
    t  = __fadd_rn(__fmul_rn(pa[7],  pb[7]),  t);
    v3 = __fadd_rn(__fmul_rn(pa[3],  pb[3]),  t);
  }
  return __fadd_rn(__fadd_rn(v0, v1), __fadd_rn(v2, v3));
}

DEV bool flt_lt(float a, float b) { return a < b || (b != b && a == a); }

// ---------- fused weight conversion (x4 vectorized) + tie-flag zero ----------
__global__ void wconv_k(const float* __restrict__ qkv_w, const float* __restrict__ proj_w,
                        const float* __restrict__ fc1_w, const float* __restrict__ fc2_w,
                        ushort_t* __restrict__ oq, ushort_t* __restrict__ op,
                        ushort_t* __restrict__ o1, ushort_t* __restrict__ o2,
                        int* __restrict__ tflag) {
  int q = blockIdx.x * 256 + threadIdx.x;
  if (q == 0) tflag[0] = 0;
  const int Q0 = 2304 * 768 / 4, Q1 = 768 * 768 / 4, Q2 = 3072 * 768 / 4, Q3 = 768 * 3072 / 4;
  const float* src; ushort_t* dst;
  if (q < Q0)      { src = qkv_w;  dst = oq; }
  else if ((q -= Q0) < Q1) { src = proj_w; dst = op; }
  else if ((q -= Q1) < Q2) { src = fc1_w;  dst = o1; }
  else if ((q -= Q2) < Q3) { src = fc2_w;  dst = o2; }
  else return;
  int i = q * 4;
  float4 v = *(const float4*)&src[i];
  uint32_t w0 = (uint32_t)f2bf(v.x) | ((uint32_t)f2bf(v.y) << 16);
  uint32_t w1 = (uint32_t)f2bf(v.z) | ((uint32_t)f2bf(v.w) << 16);
  *(uint2*)&dst[i] = make_uint2(w0, w1);
}

// ---------- fused LN1: np-exact f32 h32 (decision) + bf16 h_bf (content) + ls --
// numpy pw768 = 64 independent 12-term chains + balanced tree (shfl_xor).
__global__ __launch_bounds__(64) void fused_ln1_k(
    const float* __restrict__ x, const float* __restrict__ g, const float* __restrict__ bb,
    float* __restrict__ h32, ushort_t* __restrict__ hbf,
    const float* __restrict__ size, float* __restrict__ ls) {
  const int row = blockIdx.x, lane = threadIdx.x;
  __shared__ float xs[768];
  const float* xr = x + (size_t)row * 768;
  for (int c = lane; c < 768; c += 64) xs[c] = xr[c];
  __syncthreads();
  const int base = 96 * (lane >> 3) + (lane & 7);
  float v = xs[base];
#pragma unroll
  for (int t = 1; t < 12; t++) v = __fadd_rn(v, xs[base + 8 * t]);
#pragma unroll
  for (int w = 1; w <= 32; w <<= 1) v = __fadd_rn(v, __shfl_xor(v, w));
  const float mu = __fdiv_rn(__shfl(v, 0), 768.0f);            // np.mean
  float d0 = __fsub_rn(xs[base], mu);
  float sv = __fmul_rn(d0, d0);
#pragma unroll
  for (int t = 1; t < 12; t++) {
    float dd = __fsub_rn(xs[base + 8 * t], mu);
    sv = __fadd_rn(sv, __fmul_rn(dd, dd));
  }
#pragma unroll
  for (int w = 1; w <= 32; w <<= 1) sv = __fadd_rn(sv, __shfl_xor(sv, w));
  const float var = __fdiv_rn(__shfl(sv, 0), 768.0f);          // np.var
  const float sf = __fsqrt_rn(__fadd_rn(var, 1e-5f));          // sqrt(var+eps)
  float* hr = h32 + (size_t)row * 768;
  ushort_t* hb = hbf + (size_t)row * 768;
  for (int c = lane; c < 768; c += 64) {
    float t = __fsub_rn(xs[c], mu);
    t = __fdiv_rn(t, sf);
    t = __fmul_rn(t, g[c]);
    t = __fadd_rn(t, bb[c]);
    hr[c] = t;
    hb[c] = f2bf(t);
  }
  if (lane == 0) ls[row] = logf(size[row]);
}

// ---------- k = h @ Wk^T, kc=320-panel bit-exact, 64x64 tile, 8x4 regs ----------
__global__ __launch_bounds__(128) void kmetric32_k(
    const float* __restrict__ h32, const float* __restrict__ qkv_w, float* __restrict__ k32) {
  __shared__ float hs[64][68];
  __shared__ float wsd[64][68];
  const int tid = threadIdx.x;
  const int tx = tid & 15, ty = tid >> 4;        // tx: 16 ch-slots, ty: 8 tok-slots
  const int tok0 = blockIdx.x * 64, ch0 = blockIdx.y * 64;
  float acc[8][4];
  float part[8][4];
#pragma unroll
  for (int i = 0; i < 8; i++)
#pragma unroll
    for (int j = 0; j < 4; j++) { acc[i][j] = 0.f; part[i][j] = 0.f; }

  for (int chunk = 0; chunk < 12; chunk++) {
    const int c0 = chunk * 64;
    __syncthreads();
#pragma unroll
    for (int e = 0; e < 8; e++) {          // stage h: 64x64 floats as float4
      int flat = e * 128 + tid;
      int r = flat >> 4, c4 = (flat & 15) << 2;
      *(float4*)&hs[r][c4] = *(const float4*)&h32[(size_t)(tok0 + r) * 768 + c0 + c4];
    }
#pragma unroll
    for (int e = 0; e < 8; e++) {          // stage w: 64x64 floats as float4
      int flat = e * 128 + tid;
      int r = flat >> 4, c4 = (flat & 15) << 2;
      *(float4*)&wsd[r][c4] = *(const float4*)&qkv_w[(size_t)(768 + ch0 + r) * 768 + c0 + c4];
    }
    __syncthreads();
#pragma unroll 1
    for (int cq = 0; cq < 16; cq++) {      // 4-wide c quads, ascending
      float4 hv[8], wv[4];
#pragma unroll
      for (int i = 0; i < 8; i++) hv[i] = *(const float4*)&hs[ty + 8 * i][cq << 2];
#pragma unroll
      for (int j = 0; j < 4; j++) wv[j] = *(const float4*)&wsd[tx + 16 * j][cq << 2];
#pragma unroll
      for (int u = 0; u < 4; u++)          // ascending c within quad
#pragma unroll
        for (int i = 0; i < 8; i++) {
          float hvu = ((const float*)&hv[i])[u];
#pragma unroll
          for (int j = 0; j < 4; j++)
            acc[i][j] = __fmaf_rn(hvu, ((const float*)&wv[j])[u], acc[i][j]);
        }
    }
    if (chunk == 4) {                      // panel A done (c=320)
#pragma unroll
      for (int i = 0; i < 8; i++)
#pragma unroll
        for (int j = 0; j < 4; j++) { part[i][j] = acc[i][j]; acc[i][j] = 0.f; }
    } else if (chunk == 9) {               // panel B done (c=640): part = A + B
#pragma unroll
      for (int i = 0; i < 8; i++)
#pragma unroll
        for (int j = 0; j < 4; j++) { part[i][j] = __fadd_rn(part[i][j], acc[i][j]); acc[i][j] = 0.f; }
    }
  }
#pragma unroll
  for (int i = 0; i < 8; i++)              // final = (A+B) + C
#pragma unroll
    for (int j = 0; j < 4; j++) {
      size_t idx = (size_t)(tok0 + ty + 8 * i) * 768 + ch0 + tx + 16 * j;
      k32[idx] = __fadd_rn(part[i][j], acc[i][j]);
    }
}

// ---------- metric = k.mean(heads), L2-norm: shfl-exact np pw64; 4 rows/block --
__global__ __launch_bounds__(256) void hmean32_k(
    const float* __restrict__ k32, float* __restrict__ m32) {
  const int row = blockIdx.x * 4 + (threadIdx.x >> 6);
  const int lane = threadIdx.x & 63;
  const float* kr = k32 + (size_t)row * 768;
  float m = kr[lane];
#pragma unroll
  for (int hh = 1; hh < 12; hh++) m = __fadd_rn(m, kr[hh * 64 + lane]);
  m = __fdiv_rn(m, 12.0f);
  float sq = __fmul_rn(m, m);
  // np_pw64 via shfl: chain c = lane&7 over stride-8 (ascending), then tree.
  const int c = lane & 7;
  float r = __shfl(sq, c);
#pragma unroll
  for (int t = 1; t < 8; t++) r = __fadd_rn(r, __shfl(sq, c + 8 * t));
  r = __fadd_rn(r, __shfl_xor(r, 1));   // (r0+r1) etc (IEEE add commutative)
  r = __fadd_rn(r, __shfl_xor(r, 2));
  r = __fadd_rn(r, __shfl_xor(r, 4));
  float nrm = __fsqrt_rn(r);
  m32[(size_t)row * 64 + lane] = __fdiv_rn(m, nrm);
}

// ---------- scores: FMA screening + exact np.einsum only for candidates ------
__global__ __launch_bounds__(256) void scores32_k(
    const float* __restrict__ m32, float* __restrict__ nmax, int* __restrict__ nidx) {
  const int b = blockIdx.y, i0 = blockIdx.x * 4;
  const int tid = threadIdx.x, ig = tid >> 6, lane = tid & 63;
  const int i = i0 + ig;
  const float* mb = m32 + (size_t)b * 1568 * 64;
  __shared__ float av[4][64];
  __shared__ float appx[4][784];
  __shared__ float bv[4][64];
  __shared__ int bj[4][64];
  av[ig][lane] = mb[(size_t)(2 * i) * 64 + lane];
  __syncthreads();
  const float* a = av[ig];
  float amax = -1e30f;
  for (int j = lane; j < 784; j += 64) {     // phase 1: fused-FMA screening
    const float* br = mb + (size_t)(2 * j + 1) * 64;
    float d = 0.f;
#pragma unroll
    for (int c = 0; c < 64; c++) d = __fmaf_rn(a[c], br[c], d);
    appx[ig][j] = d;
    amax = fmaxf(amax, d);
  }
#pragma unroll
  for (int w = 1; w < 64; w <<= 1) amax = fmaxf(amax, __shfl_xor(amax, w));
  const float thr = amax - 1e-4f;
  float best = -1e30f; int bidx = 0;
  for (int j = lane; j < 784; j += 64) {     // phase 2: exact recipe, candidates only
    if (appx[ig][j] >= thr) {
      const float* br = mb + (size_t)(2 * j + 1) * 64;
      float dot = np_einsum_dot64(a, br);
      if (dot > best) { best = dot; bidx = j; }   // ascending j -> first max kept
    }
  }
  bv[ig][lane] = best; bj[ig][lane] = bidx;
  __syncthreads();
  if (lane == 0) {
    float bb_ = bv[ig][0]; int bi_ = bj[ig][0];
    for (int l = 1; l < 64; l++)
      if (bv[ig][l] > bb_ || (bv[ig][l] == bb_ && bj[ig][l] < bi_)) { bb_ = bv[ig][l]; bi_ = bj[ig][l]; }
    nmax[b * 784 + i] = bb_;                 // max exact; argmax = first max
    nidx[b * 784 + i] = bi_;
  }
}

// ---------- FAST PATH: parallel stable-descending rank sort + tie detection ----
__global__ __launch_bounds__(256) void rank_fast_k(
    const float* __restrict__ nmax, const int* __restrict__ nidx,
    int* __restrict__ eidx, int* __restrict__ didx, int* __restrict__ tflag) {
  const int b = blockIdx.x;
  __shared__ float sv[784];
  __shared__ int s_ei[784];
  for (int i = threadIdx.x; i < 784; i += 256) sv[i] = nmax[b * 784 + i];
  __syncthreads();
  for (int i = threadIdx.x; i < 784; i += 256) {
    float v = sv[i]; int rank = 0;
    for (int j = 0; j < 784; j++) {
      float u = sv[j];
      rank += (u > v || (u == v && j < i)) ? 1 : 0;
    }
    s_ei[rank] = i;
  }
  __syncthreads();
  for (int r = threadIdx.x; r < 783; r += 256)
    if (sv[s_ei[r]] == sv[s_ei[r + 1]]) atomicOr(tflag, 1);
  for (int i = threadIdx.x; i < 784; i += 256) eidx[b * 784 + i] = s_ei[i];
  for (int i = threadIdx.x; i < 256; i += 256) didx[b * 256 + i] = nidx[b * 784 + s_ei[i]];
}

// ---------- SLOW PATH: faithful numpy aquicksort; runs only if ties exist ----
__global__ __launch_bounds__(64) void argsort_serial_k(
    const float* __restrict__ nmax, const int* __restrict__ nidx,
    int* __restrict__ eidx, int* __restrict__ didx, const int* __restrict__ tflag) {
  if (tflag[0] == 0) return;                 // no exact ties: fast path already exact
  const int b = blockIdx.x;
  __shared__ float sv[784];
  __shared__ int tos[784];
  for (int i = threadIdx.x; i < 784; i += 64) { sv[i] = -nmax[b * 784 + i]; tos[i] = i; }
  __syncthreads();
  if (threadIdx.x == 0) {
    const int num = 784;
    int stck[100]; int sptr = 0;
    int dpth[100]; int psd = 0;
    int cdepth; { int n = num, m = 0; while (n >>= 1) m++; cdepth = m * 2; }  // 18
    int pl = 0, pr = num - 1;
    for (;;) {
      if (cdepth < 0) {                       // aheapsort fallback (numpy-faithful)
        int n = pr - pl + 1;
        int* a = &tos[pl] - 1;                // 1-based
        for (int l = n >> 1; l > 0; --l) {
          int tmp = a[l];
          int i2 = l, j2 = l * 2;
          while (j2 <= n) {
            if (j2 < n && flt_lt(sv[a[j2]], sv[a[j2 + 1]])) j2++;
            if (flt_lt(sv[tmp], sv[a[j2]])) { a[i2] = a[j2]; i2 = j2; j2 += j2; }
            else break;
          }
          a[i2] = tmp;
        }
        for (int n2 = n; n2 > 1;) {
          int tmp = a[n2]; a[n2] = a[1]; n2--;
          int i2 = 1, j2 = 2;
          while (j2 <= n2) {
            if (j2 < n2 && flt_lt(sv[a[j2]], sv[a[j2 + 1]])) j2++;
            if (flt_lt(sv[tmp], sv[a[j2]])) { a[i2] = a[j2]; i2 = j2; j2 += j2; }
            else break;
          }
          a[i2] = tmp;
        }
        goto stack_pop;
      }
      while ((pr - pl) > 15) {                // SMALL_QUICKSORT = 15
        int t_;
        int pm = pl + ((pr - pl) >> 1);
        if (flt_lt(sv[tos[pm]], sv[tos[pl]])) { t_ = tos[pm]; tos[pm] = tos[pl]; tos[pl] = t_; }
        if (flt_lt(sv[tos[pr]], sv[tos[pm]])) { t_ = tos[pr]; tos[pr] = tos[pm]; tos[pm] = t_; }
        if (flt_lt(sv[tos[pm]], sv[tos[pl]])) { t_ = tos[pm]; tos[pm] = tos[pl]; tos[pl] = t_; }
        float vp = sv[tos[pm]];
        int pi = pl, pj = pr - 1;
        t_ = tos[pm]; tos[pm] = tos[pj]; tos[pj] = t_;
        for (;;) {
          do { ++pi; } while (flt_lt(sv[tos[pi]], vp));
          do { --pj; } while (flt_lt(vp, sv[tos[pj]]));
          if (pi >= pj) break;
          t_ = tos[pi]; tos[pi] = tos[pj]; tos[pj] = t_;
        }
        int pk = pr - 1;
        t_ = tos[pi]; tos[pi] = tos[pk]; tos[pk] = t_;
        if (pi - pl < pr - pi) { stck[sptr++] = pi + 1; stck[sptr++] = pr; pr = pi - 1; }
        else                   { stck[sptr++] = pl; stck[sptr++] = pi - 1; pl = pi + 1; }
        dpth[psd++] = --cdepth;
      }
      for (int pi2 = pl + 1; pi2 <= pr; pi2++) {   // insertion sort tail
        int vi = tos[pi2]; float vp2 = sv[vi];
        int pj2 = pi2, pk2 = pi2 - 1;
        while (pj2 > pl && flt_lt(vp2, sv[tos[pk2]])) { tos[pj2--] = tos[pk2--]; }
        tos[pj2] = vi;
      }
stack_pop:
      if (sptr == 0) break;
      pr = stck[--sptr]; pl = stck[--sptr];
      cdepth = dpth[--psd];
    }
  }
  __syncthreads();
  for (int i = threadIdx.x; i < 784; i += 64) eidx[b * 784 + i] = tos[i];
  for (int i = threadIdx.x; i < 256; i += 64) didx[b * 256 + i] = nidx[b * 784 + tos[i]];
}

// ---------- LayerNorm -> bf16 (content path, LN2) ----------
__global__ __launch_bounds__(256) void ln_k(
    const float* __restrict__ x, const float* __restrict__ g, const float* __restrict__ bb,
    ushort_t* __restrict__ hout, const float* __restrict__ size, float* __restrict__ ls) {
  const int row = blockIdx.x;
  const float* xr = x + (size_t)row * 768;
  const int t = threadIdx.x;
  float v0 = xr[t], v1 = xr[t + 256], v2 = xr[t + 512];
  float s = v0 + v1 + v2;
  float ss = v0 * v0 + v1 * v1 + v2 * v2;
#pragma unroll
  for (int w = 32; w >= 1; w >>= 1) { s += __shfl_down(s, w); ss += __shfl_down(ss, w); }
  __shared__ float red[8];
  const int wv = t >> 6;
  if ((t & 63) == 0) { red[wv] = s; red[4 + wv] = ss; }
  __syncthreads();
  s  = red[0] + red[1] + red[2] + red[3];
  ss = red[4] + red[5] + red[6] + red[7];
  const float mu = s * (1.f / 768.f);
  const float rstd = rsqrtf(ss * (1.f / 768.f) - mu * mu + 1e-5f);
  ushort_t* hr = hout + (size_t)row * 768;
  hr[t]       = f2bf((v0 - mu) * rstd * g[t]       + bb[t]);
  hr[t + 256] = f2bf((v1 - mu) * rstd * g[t + 256] + bb[t + 256]);
  hr[t + 512] = f2bf((v2 - mu) * rstd * g[t + 512] + bb[t + 512]);
  if (ls != nullptr && t == 0) ls[row] = logf(size[row]);
}

// ---------- GEMM: C[M,N] = A[M,K](bf16) @ W[N,K]^T(bf16), epilogue per EPI ----------
template <int EPI>
__global__ __launch_bounds__(256) void gemm_bt(
    const ushort_t* __restrict__ A, const ushort_t* __restrict__ W, int K,
    const float* __restrict__ bias0, const float* __restrict__ bias1,
    const float* __restrict__ res,
    ushort_t* __restrict__ ob0, ushort_t* __restrict__ ob1, ushort_t* __restrict__ ob2,
    float* __restrict__ of) {
  __shared__ ushort_t As[128 * 32];   // unpadded: required by global_load_lds
  __shared__ ushort_t Bs[128 * 32];
  const int tid = threadIdx.x;
  const int lane = tid & 63, wave = tid >> 6;
  const int wm = (wave >> 1) * 64, wn = (wave & 1) * 64;
  const int fr = lane & 15, kb = (lane >> 4) * 8;
  const int bm = blockIdx.x * 128, bn = blockIdx.y * 128;
  const int rr = tid >> 2;                  // 0..63 (row within chunk)
  const int cb = (tid & 3) * 8;             // ushort col offset (16B quanta)
  ushort_t* ldA0 = As + wave * 512;         // chunk 0 wave base (512 ush = 1KB)
  ushort_t* ldA1 = As + 2048 + wave * 512;  // chunk 1
  ushort_t* ldB0 = Bs + wave * 512;
  ushort_t* ldB1 = Bs + 2048 + wave * 512;
  f32x4 acc[4][4] = {};
  for (int k0 = 0; k0 < K; k0 += 32) {
    __syncthreads();                        // previous tile reads done
    gload_lds16(A + (size_t)(bm + rr) * K + k0 + cb,      ldA0);
    gload_lds16(A + (size_t)(bm + 64 + rr) * K + k0 + cb, ldA1);
    gload_lds16(W + (size_t)(bn + rr) * K + k0 + cb,      ldB0);
    gload_lds16(W + (size_t)(bn + 64 + rr) * K + k0 + cb, ldB1);
    __syncthreads();                        // vmcnt(0) drain: data in LDS
    bf16x8 af[4], bfr[4];
#pragma unroll
    for (int i = 0; i < 4; i++) af[i]  = ld_frag_lds(&As[(wm + i * 16 + fr) * 32 + kb]);
#pragma unroll
    for (int i = 0; i < 4; i++) bfr[i] = ld_frag_lds(&Bs[(wn + i * 16 + fr) * 32 + kb]);
#pragma unroll
    for (int mi = 0; mi < 4; mi++)
#pragma unroll
      for (int ni = 0; ni < 4; ni++)
        acc[mi][ni] = mfma16(af[mi], bfr[ni], acc[mi][ni]);
  }
#pragma unroll
  for (int mi = 0; mi < 4; mi++)
#pragma unroll
    for (int ni = 0; ni < 4; ni++)
#pragma unroll
      for (int e = 0; e < 4; e++) {
        int m = bm + wm + mi * 16 + (lane >> 4) * 4 + e;
        int j = bn + wn + ni * 16 + fr;
        float val = acc[mi][ni][e];
        if constexpr (EPI == 0) {  // qkv -> q,k (B,H,N,D) ; v -> vt (B,H,D,N)
          int which = j / 768;
          int loc = j - which * 768;
          int hh = loc >> 6, d = loc & 63;
          unsigned um = (unsigned)m;
          unsigned b = um / 1568u;
          unsigned n = um - b * 1568u;
          if (which == 0) {
            val = (val + bias0[loc]) * 0.125f;
            ob0[(((size_t)b * 12 + hh) * 1568 + n) * 64 + d] = f2bf(val);
          } else if (which == 1) {
            ob1[(((size_t)b * 12 + hh) * 1568 + n) * 64 + d] = f2bf(val);
          } else {
            val += bias1[loc];
            ob2[(((size_t)b * 12 + hh) * 64 + d) * 1568 + n] = f2bf(val);
          }
        } else if constexpr (EPI == 1) {        // proj: + bias + x residual -> f32
          size_t idx = (size_t)m * 768 + j;
          of[idx] = val + bias0[j] + res[idx];
        } else if constexpr (EPI == 2) {        // fc1: + bias, exact GELU -> bf16
          float v = val + bias0[j];
          v = 0.5f * v * (1.0f + erff(v * 0.70710678118654752f));
          ob0[(size_t)m * 3072 + j] = f2bf(v);
        } else {                                // fc2: + bias + xm (in-place d_out)
          size_t idx = (size_t)m * 768 + j;
          of[idx] = val + bias0[j] + of[idx];
        }
      }
}

// ---------- flash attention: 7 waves/block share K/V via LDS (7x reuse) ----------
__global__ __launch_bounds__(448) void attn_k(
    const ushort_t* __restrict__ q, const ushort_t* __restrict__ k,
    const ushort_t* __restrict__ vt, const float* __restrict__ ls,
    ushort_t* __restrict__ o) {
  const int h = blockIdx.y, b = blockIdx.z;
  const int tid = threadIdx.x, wave = tid >> 6, lane = tid & 63;
  const int fr = lane & 15, hi = lane >> 4, kb = hi * 8;
  const ushort_t* qb  = q  + (size_t)(b * 12 + h) * 1568 * 64;
  const ushort_t* kbp = k  + (size_t)(b * 12 + h) * 1568 * 64;
  const ushort_t* vtb = vt + (size_t)(b * 12 + h) * 64 * 1568;
  const float* lsb = ls + b * 1568;
  const int q0 = (blockIdx.x * 7 + wave) * 16;   // 14*7 = 98 q-tiles exact
  __shared__ ushort_t Ks[2][32][68];   // [buf][key][d]   (+4 pad)
  __shared__ ushort_t Vs[2][64][36];   // [buf][d][key]   (+4 pad)
  __shared__ ushort_t Pls[7][16][36];  // per-wave P
  bf16x8 aq0 = ld_frag_g(qb + (size_t)(q0 + fr) * 64 + kb);
  bf16x8 aq1 = ld_frag_g(qb + (size_t)(q0 + fr) * 64 + 32 + kb);
  float m_r = -1e30f, l_r = 0.f;
  f32x4 oacc[4] = {};
  const bool doK = (tid < 256);
  const int krow = tid >> 3, kcol = (tid & 7) * 8;
  const int vtid = tid - 192;
  const bool doV = (vtid >= 0);
  const int vrow = vtid >> 2, vcol = (vtid & 3) * 8;
  if (doK) {
    uint4 kv = *(const uint4*)(kbp + (size_t)krow * 64 + kcol);
    *(uint2*)&Ks[0][krow][kcol]     = make_uint2(kv.x, kv.y);
    *(uint2*)&Ks[0][krow][kcol + 4] = make_uint2(kv.z, kv.w);
  }
  if (doV) {
    uint4 vv = *(const uint4*)(vtb + (size_t)vrow * 1568 + vcol);
    *(uint2*)&Vs[0][vrow][vcol]     = make_uint2(vv.x, vv.y);
    *(uint2*)&Vs[0][vrow][vcol + 4] = make_uint2(vv.z, vv.w);
  }
  __syncthreads();
  for (int kt = 0; kt < 49; kt++) {
    const int key0 = kt * 32;
    const int cur = kt & 1;
    uint4 kvn, vvn;                        // issue next-tile loads early (T14)
    if (kt < 48) {
      if (doK) kvn = *(const uint4*)(kbp + (size_t)(key0 + 32 + krow) * 64 + kcol);
      if (doV) vvn = *(const uint4*)(vtb + (size_t)vrow * 1568 + key0 + 32 + vcol);
    }
    bf16x8 c0a = ld_frag_lds(&Ks[cur][fr][kb]);
    bf16x8 c0b = ld_frag_lds(&Ks[cur][fr][32 + kb]);
    bf16x8 c1a = ld_frag_lds(&Ks[cur][16 + fr][kb]);
    bf16x8 c1b = ld_frag_lds(&Ks[cur][16 + fr][32 + kb]);
    f32x4 sl = {0, 0, 0, 0}, sh = {0, 0, 0, 0};
    sl = mfma16(c0a, aq0, sl); sl = mfma16(c0b, aq1, sl);
    sh = mfma16(c1a, aq0, sh); sh = mfma16(c1b, aq1, sh);
    float4 lsl = *(const float4*)&lsb[key0 + hi * 4];
    float4 lsh = *(const float4*)&lsb[key0 + 16 + hi * 4];
    float v0 = sl[0] + lsl.x, v1 = sl[1] + lsl.y, v2 = sl[2] + lsl.z, v3 = sl[3] + lsl.w;
    float v4 = sh[0] + lsh.x, v5 = sh[1] + lsh.y, v6 = sh[2] + lsh.z, v7 = sh[3] + lsh.w;
    float mx = fmaxf(fmaxf(fmaxf(v0, v1), fmaxf(v2, v3)),
                     fmaxf(fmaxf(v4, v5), fmaxf(v6, v7)));
    mx = fmaxf(mx, __shfl_xor(mx, 16));
    mx = fmaxf(mx, __shfl_xor(mx, 32));    // row max over 32 keys
    if (!__all(mx <= m_r)) {               // exact defer-max
      float mnew = fmaxf(m_r, mx);
      float corr = __expf(m_r - mnew);
      m_r = mnew;
      l_r *= corr;
      float cb0 = __shfl(corr, hi * 4 + 0);
      float cb1 = __shfl(corr, hi * 4 + 1);
      float cb2 = __shfl(corr, hi * 4 + 2);
      float cb3 = __shfl(corr, hi * 4 + 3);
#pragma unroll
      for (int dt = 0; dt < 4; dt++) {
        oacc[dt][0] *= cb0; oacc[dt][1] *= cb1;
        oacc[dt][2] *= cb2; oacc[dt][3] *= cb3;
      }
    }
    float p0 = __expf(v0 - m_r), p1 = __expf(v1 - m_r);
    float p2 = __expf(v2 - m_r), p3 = __expf(v3 - m_r);
    float p4 = __expf(v4 - m_r), p5 = __expf(v5 - m_r);
    float p6 = __expf(v6 - m_r), p7 = __expf(v7 - m_r);
    float ps = ((p0 + p1) + (p2 + p3)) + ((p4 + p5) + (p6 + p7));
    ps += __shfl_xor(ps, 16);
    ps += __shfl_xor(ps, 32);
    l_r += ps;
    uint32_t w0 = (uint32_t)f2bf(p0) | ((uint32_t)f2bf(p1) << 16);
    uint32_t w1 = (uint32_t)f2bf(p2) | ((uint32_t)f2bf(p3) << 16);
    uint32_t w2 = (uint32_t)f2bf(p4) | ((uint32_t)f2bf(p5) << 16);
    uint32_t w3 = (uint32_t)f2bf(p6) | ((uint32_t)f2bf(p7) << 16);
    *(uint2*)&Pls[wave][fr][hi * 4]      = make_uint2(w0, w1);
    *(uint2*)&Pls[wave][fr][16 + hi * 4] = make_uint2(w2, w3);
    bf16x8 pa = ld_frag_lds(&Pls[wave][fr][kb]);
#pragma unroll
    for (int dt = 0; dt < 4; dt++) {
      bf16x8 bvv = ld_frag_lds(&Vs[cur][dt * 16 + fr][kb]);
      oacc[dt] = mfma16(pa, bvv, oacc[dt]);
    }
    if (kt < 48) {
      if (doK) {
        *(uint2*)&Ks[cur ^ 1][krow][kcol]     = make_uint2(kvn.x, kvn.y);
        *(uint2*)&Ks[cur ^ 1][krow][kcol + 4] = make_uint2(kvn.z, kvn.w);
      }
      if (doV) {
        *(uint2*)&Vs[cur ^ 1][vrow][vcol]     = make_uint2(vvn.x, vvn.y);
        *(uint2*)&Vs[cur ^ 1][vrow][vcol + 4] = make_uint2(vvn.z, vvn.w);
      }
    }
    __syncthreads();
  }
  float lb[4];
#pragma unroll
  for (int e = 0; e < 4; e++) lb[e] = __shfl(l_r, hi * 4 + e);
  const size_t obase = ((size_t)b * 1568 + q0) * 768 + h * 64;
#pragma unroll
  for (int dt = 0; dt < 4; dt++)
#pragma unroll
    for (int e = 0; e < 4; e++)
      o[obase + (size_t)(hi * 4 + e) * 768 + dt * 16 + fr] = f2bf(oacc[dt][e] / lb[e]);
}

// ---------- token merge: deterministic gather (hoisted src-list scan) ----------
__global__ __launch_bounds__(256) void merge_k(
    const float* __restrict__ xa, const float* __restrict__ size,
    const int* __restrict__ eidx, const int* __restrict__ didx,
    float* __restrict__ xm) {
  const int b = blockIdx.y, t = blockIdx.x;
  const float* xab = xa + (size_t)b * 1568 * 768;
  const float* szb = size + (size_t)b * 1568;
  const int* ei = eidx + b * 784;
  const int* di = didx + b * 256;
  float* outr = xm + ((size_t)b * 1312 + t) * 768;
  if (t < 528) {
    int tok = 2 * ei[256 + t];
    float s = szb[tok];
    const float* xr = xab + (size_t)tok * 768;
    for (int c = threadIdx.x; c < 768; c += 256) outr[c] = (xr[c] * s) / s;
  } else {
    int j = t - 528;
    int tok = 2 * j + 1;
    __shared__ int lst[256];
    __shared__ int s_cnt;
    __shared__ float s_sn;
    if (threadIdx.x == 0) {
      int cnt = 0;
      float sn = szb[tok];
      for (int s_ = 0; s_ < 256; s_++)
        if (di[s_] == j) { int st = 2 * ei[s_]; lst[cnt++] = st; sn += szb[st]; }
      s_cnt = cnt; s_sn = sn;
    }
    __syncthreads();
    const int n = s_cnt;
    const float sn = s_sn;
    for (int c = threadIdx.x; c < 768; c += 256) {
      float val = xab[(size_t)tok * 768 + c] * szb[tok];
      for (int l = 0; l < n; l++) {      // ascending s_ order preserved
        int st = lst[l];
        val += xab[(size_t)st * 768 + c] * szb[st];
      }
      outr[c] = val / sn;
    }
  }
}

// ---------- workspace layout ----------
static const size_t OFF_QKVW  = 0;                          // 2304*768*2
static const size_t OFF_PROJW = OFF_QKVW  + 3538944;        // 768*768*2
static const size_t OFF_FC1W  = OFF_PROJW + 1179648;        // 3072*768*2
static const size_t OFF_FC2W  = OFF_FC1W  + 4718592;        // 768*3072*2
static const size_t OFF_LS    = OFF_FC2W  + 4718592;        // 6272*4
static const size_t OFF_MET   = OFF_LS    + 25088;          // 6272*64*4 (m32)
static const size_t OFF_NMAX  = OFF_MET   + 1605632;        // 4*784*4
static const size_t OFF_NIDX  = OFF_NMAX  + 12544;
static const size_t OFF_EIDX  = OFF_NIDX  + 12544;
static const size_t OFF_DIDX  = OFF_EIDX  + 12544;          // 4*256*4
static const size_t OFF_TFLAG = OFF_DIDX  + 4096;           // tie flag (+pad)
static const size_t OFF_H     = OFF_TFLAG + 256;            // h_bf16 (6272*768*2)
static const size_t OFF_BIG   = OFF_H     + 9633792;        // q,k,vt | h3 | k32 alias
static const size_t OFF_O     = OFF_BIG   + 32243712;       // o_bf16
static const size_t OFF_XA    = OFF_O     + 9633792;        // xa f32 | h32 alias
static const size_t WS_NEED   = OFF_XA    + 19267584;       // ~86.6 MB

extern "C" void kernel_launch(void* const* d_in, const int* in_sizes, int n_in,
                              void* d_out, int out_size, void* d_ws, size_t ws_size,
                              hipStream_t stream) {
  (void)in_sizes; (void)n_in; (void)out_size;
  if (ws_size < WS_NEED) return;

  const float* x      = (const float*)d_in[0];
  const float* size_p = (const float*)d_in[1];
  const float* qkv_w  = (const float*)d_in[2];
  const float* q_bias = (const float*)d_in[3];
  const float* v_bias = (const float*)d_in[4];
  const float* proj_w = (const float*)d_in[5];
  const float* proj_b = (const float*)d_in[6];
  const float* ln1_g  = (const float*)d_in[7];
  const float* ln1_b  = (const float*)d_in[8];
  const float* ln2_g  = (const float*)d_in[9];
  const float* ln2_b  = (const float*)d_in[10];
  const float* fc1_w  = (const float*)d_in[11];
  const float* fc1_b  = (const float*)d_in[12];
  const float* fc2_w  = (const float*)d_in[13];
  const float* fc2_b  = (const float*)d_in[14];

  char* ws = (char*)d_ws;
  ushort_t* qkvw_bf = (ushort_t*)(ws + OFF_QKVW);
  ushort_t* projw_bf= (ushort_t*)(ws + OFF_PROJW);
  ushort_t* fc1w_bf = (ushort_t*)(ws + OFF_FC1W);
  ushort_t* fc2w_bf = (ushort_t*)(ws + OFF_FC2W);
  float*    ls      = (float*)   (ws + OFF_LS);
  float*    m32     = (float*)   (ws + OFF_MET);
  float*    nmax    = (float*)   (ws + OFF_NMAX);
  int*      nidx    = (int*)     (ws + OFF_NIDX);
  int*      eidx    = (int*)     (ws + OFF_EIDX);
  int*      didx    = (int*)     (ws + OFF_DIDX);
  int*      tflag   = (int*)     (ws + OFF_TFLAG);
  ushort_t* h_bf    = (ushort_t*)(ws + OFF_H);
  ushort_t* q_bf    = (ushort_t*)(ws + OFF_BIG);
  ushort_t* k_bf    = (ushort_t*)(ws + OFF_BIG + 9633792);
  ushort_t* vt_bf   = (ushort_t*)(ws + OFF_BIG + 2 * 9633792);
  ushort_t* h3_bf   = (ushort_t*)(ws + OFF_BIG);
  float*    k32     = (float*)   (ws + OFF_BIG);   // alias: dead before gemm<0>
  ushort_t* o_bf    = (ushort_t*)(ws + OFF_O);
  float*    xa      = (float*)   (ws + OFF_XA);
  float*    h32     = (float*)   (ws + OFF_XA);    // alias: dead before gemm<1>
  float*    out     = (float*)d_out;

  // weights -> bf16 (fused, x4 vectorized, also zeroes tie flag)
  wconv_k<<<6912, 256, 0, stream>>>(qkv_w, proj_w, fc1_w, fc2_w,
                                    qkvw_bf, projw_bf, fc1w_bf, fc2w_bf, tflag);

  // ---- fused LN1: h32 (np-exact decision) + h_bf (content) + ls ----
  fused_ln1_k<<<6272, 64, 0, stream>>>(x, ln1_g, ln1_b, h32, h_bf, size_p, ls);

  // ---- decision path: exact numpy-f32 mimic (kc=320 GEMM panels) ----
  kmetric32_k<<<dim3(98, 12), 128, 0, stream>>>(h32, qkv_w, k32);
  hmean32_k<<<1568, 256, 0, stream>>>(k32, m32);
  scores32_k<<<dim3(196, 4), 256, 0, stream>>>(m32, nmax, nidx);
  rank_fast_k<<<4, 256, 0, stream>>>(nmax, nidx, eidx, didx, tflag);        // fast path
  argsort_serial_k<<<4, 64, 0, stream>>>(nmax, nidx, eidx, didx, tflag);    // tie fallback

  // ---- content path: bf16 MFMA ----
  gemm_bt<0><<<dim3(49, 18), 256, 0, stream>>>(h_bf, qkvw_bf, 768, q_bias, v_bias,
                                               nullptr, q_bf, k_bf, vt_bf, nullptr);
  attn_k<<<dim3(14, 12, 4), 448, 0, stream>>>(q_bf, k_bf, vt_bf, ls, o_bf);
  gemm_bt<1><<<dim3(49, 6), 256, 0, stream>>>(o_bf, projw_bf, 768, proj_b, nullptr,
                                              x, nullptr, nullptr, nullptr, xa);

  merge_k<<<dim3(1312, 4), 256, 0, stream>>>(xa, size_p, eidx, didx, out);

  ln_k<<<5248, 256, 0, stream>>>(out, ln2_g, ln2_b, h_bf, nullptr, nullptr);
  gemm_bt<2><<<dim3(41, 24), 256, 0, stream>>>(h_bf, fc1w_bf, 768, fc1_b, nullptr,
                                               nullptr, h3_bf, nullptr, nullptr, nullptr);
  gemm_bt<3><<<dim3(41, 6), 256, 0, stream>>>(h3_bf, fc2w_bf, 3072, fc2_b, nullptr,
                                              nullptr, nullptr, nullptr, nullptr, out);
}